// Round 5
// baseline (345.277 us; speedup 1.0000x reference)
//
#include <hip/hip_runtime.h>
#include <hip/hip_bf16.h>

using bf16 = __hip_bfloat16;
typedef __attribute__((ext_vector_type(8))) __bf16 bf16x8;
typedef __attribute__((ext_vector_type(4))) float floatx4;

#define B_  16
#define T_  1024
#define C_  768
#define M_  16384  // B_*T_

#define OFF_XK ((size_t)0)
#define OFF_XV ((size_t)25165824)
#define OFF_XR ((size_t)50331648)
#define OFF_K  ((size_t)75497472)
#define OFF_V  ((size_t)100663296)
#define OFF_SR ((size_t)125829120)
#define OFF_WT ((size_t)150994944)
#define OFF_Y  ((size_t)0)          // bf16 yT aliases xk (dead after mix3)
#define OFF_Z  ((size_t)50331648)   // bf16 z aliases xr (dead after mix3)

struct __align__(16) BV8 { bf16 v[8]; };

// ================= prep: transpose_w + shift_mix merged =================
// blocks [0, 6144): shift_mix ; blocks [6144, 8448): weight transpose
__global__ __launch_bounds__(256) void prep_kernel(
    const float* __restrict__ x,
    const float* __restrict__ mk, const float* __restrict__ mv, const float* __restrict__ mr,
    const float* __restrict__ w0, const float* __restrict__ w1,
    const float* __restrict__ w2, const float* __restrict__ w3,
    bf16* __restrict__ xk, bf16* __restrict__ xv, bf16* __restrict__ xr,
    bf16* __restrict__ wt) {
  __shared__ float tile[32 * 33];
  int bid = blockIdx.x;
  if (bid < 6144) {
    int gid = bid * 256 + threadIdx.x;
    int c8 = gid % 96;
    int bt = gid / 96;
    int b  = bt >> 10;
    int t  = bt & 1023;
    int hh = t >> 5, ww = t & 31;
    int c0 = c8 * 8;
    int g  = c8 / 24;
    int sh = hh, sw = ww;
    bool valid;
    if (g == 0)      { sw = ww - 1; valid = (ww >= 1);  }
    else if (g == 1) { sw = ww + 1; valid = (ww <= 30); }
    else if (g == 2) { sh = hh - 1; valid = (hh >= 1);  }
    else             { sh = hh + 1; valid = (hh <= 30); }
    size_t off = (size_t)bt * C_ + c0;
    float xs[8], ss[8];
    *(float4*)(xs)     = *(const float4*)(x + off);
    *(float4*)(xs + 4) = *(const float4*)(x + off + 4);
    if (valid) {
      size_t soff = (size_t)(b * 1024 + sh * 32 + sw) * C_ + c0;
      *(float4*)(ss)     = *(const float4*)(x + soff);
      *(float4*)(ss + 4) = *(const float4*)(x + soff + 4);
    } else {
#pragma unroll
      for (int j = 0; j < 8; j++) ss[j] = 0.f;
    }
    BV8 ok, ov, orr;
#pragma unroll
    for (int j = 0; j < 8; j++) {
      float xf = xs[j], sf = ss[j];
      float a  = mk[c0 + j];
      float bm = mv[c0 + j];
      float cm = mr[c0 + j];
      ok.v[j]  = __float2bfloat16(xf * a  + sf * (1.f - a));
      ov.v[j]  = __float2bfloat16(xf * bm + sf * (1.f - bm));
      orr.v[j] = __float2bfloat16(xf * cm + sf * (1.f - cm));
    }
    *(BV8*)(xk + off) = ok;
    *(BV8*)(xv + off) = ov;
    *(BV8*)(xr + off) = orr;
  } else {
    int tb = bid - 6144;
    int which = tb / 576;
    int rem   = tb % 576;
    int by = rem / 24, bx = rem % 24;
    const float* src = which == 0 ? w0 : which == 1 ? w1 : which == 2 ? w2 : w3;
    bf16* dst = wt + (size_t)which * (C_ * C_);
    int k0 = by * 32;
    int n0 = bx * 32;
    int j  = threadIdx.x & 31;
    int i0 = threadIdx.x >> 5;
#pragma unroll
    for (int s = 0; s < 4; s++) {
      int i = i0 + s * 8;
      tile[i * 33 + j] = src[(size_t)(k0 + i) * C_ + n0 + j];
    }
    __syncthreads();
#pragma unroll
    for (int s = 0; s < 4; s++) {
      int i = i0 + s * 8;
      dst[(size_t)(n0 + i) * C_ + k0 + j] = __float2bfloat16(tile[j * 33 + i]);
    }
  }
}

// ---- shared GEMM body: 128x128 tile, BK=64 as two BK=32 panels ----
template <int MODE>
__device__ __forceinline__ void gemm_body(
    const bf16* __restrict__ A, const bf16* __restrict__ BT,
    void* __restrict__ Cout, int M, int N, int K,
    int bx, int by) {
  __shared__ bf16 As[128 * 64];
  __shared__ bf16 Bs[128 * 64];
  int tid  = threadIdx.x;
  int wave = tid >> 6, lane = tid & 63;
  int wm = (wave & 1) * 64, wn = (wave >> 1) * 64;
  size_t m0 = (size_t)by * 128, n0 = (size_t)bx * 128;

  floatx4 acc[4][4];
#pragma unroll
  for (int i = 0; i < 4; i++)
#pragma unroll
    for (int j = 0; j < 4; j++) acc[i][j] = (floatx4){0.f, 0.f, 0.f, 0.f};

  int srow[4], skk[4];
#pragma unroll
  for (int i = 0; i < 4; i++) {
    srow[i] = ((tid >> 2) + i * 64) & 127;
    skk[i]  = (tid & 3) * 8 + (i >> 1) * 32;
  }
  bf16* lA = As + tid * 8;
  bf16* lB = Bs + tid * 8;
  int fr  = lane & 15;
  int fko = (lane >> 4) * 8;

  for (int k0 = 0; k0 < K; k0 += 64) {
#pragma unroll
    for (int i = 0; i < 4; i++) {
      __builtin_amdgcn_global_load_lds(
          (const __attribute__((address_space(1))) void*)(A + (m0 + srow[i]) * (size_t)K + k0 + skk[i]),
          (__attribute__((address_space(3))) void*)(lA + i * 2048), 16, 0, 0);
      __builtin_amdgcn_global_load_lds(
          (const __attribute__((address_space(1))) void*)(BT + (n0 + srow[i]) * (size_t)K + k0 + skk[i]),
          (__attribute__((address_space(3))) void*)(lB + i * 2048), 16, 0, 0);
    }
    __syncthreads();
#pragma unroll
    for (int s = 0; s < 2; s++) {
      bf16x8 af[4], bfr[4];
#pragma unroll
      for (int mi = 0; mi < 4; mi++)
        af[mi] = *(const bf16x8*)(As + s * 4096 + (wm + mi * 16 + fr) * 32 + fko);
#pragma unroll
      for (int ni = 0; ni < 4; ni++)
        bfr[ni] = *(const bf16x8*)(Bs + s * 4096 + (wn + ni * 16 + fr) * 32 + fko);
#pragma unroll
      for (int mi = 0; mi < 4; mi++)
#pragma unroll
        for (int ni = 0; ni < 4; ni++)
          acc[mi][ni] = __builtin_amdgcn_mfma_f32_16x16x32_bf16(
              af[mi], bfr[ni], acc[mi][ni], 0, 0, 0);
    }
    __syncthreads();
  }
  int cr = (lane >> 4) * 4;
  int cc = lane & 15;
#pragma unroll
  for (int mi = 0; mi < 4; mi++)
#pragma unroll
    for (int ni = 0; ni < 4; ni++)
#pragma unroll
      for (int i = 0; i < 4; i++) {
        size_t r   = m0 + wm + mi * 16 + cr + i;
        size_t col = n0 + wn + ni * 16 + cc;
        float val = acc[mi][ni][i];
        if (MODE == 3) {
          ((float*)Cout)[r * N + col] = val;
        } else {
          if (MODE == 2) val = 1.0f / (1.0f + __expf(-val));
          ((bf16*)Cout)[r * N + col] = __float2bfloat16(val);
        }
      }
}

template <int MODE>
__global__ __launch_bounds__(256, 2) void gemm_bt(
    const bf16* __restrict__ A, const bf16* __restrict__ BT,
    void* __restrict__ Cout, int M, int N, int K) {
  gemm_body<MODE>(A, BT, Cout, M, N, K, blockIdx.x, blockIdx.y);
}

// merged k^T / v^T / sr^T GEMM: blockIdx.z selects operand set (2 = sigmoid)
__global__ __launch_bounds__(256, 2) void gemm_mix3(
    const bf16* __restrict__ A0, const bf16* __restrict__ B0, bf16* __restrict__ C0,
    const bf16* __restrict__ A1, const bf16* __restrict__ B1, bf16* __restrict__ C1,
    const bf16* __restrict__ A2, const bf16* __restrict__ B2, bf16* __restrict__ C2,
    int M, int N, int K) {
  int z = blockIdx.z;
  if (z == 0)
    gemm_body<1>(A0, B0, C0, M, N, K, blockIdx.x, blockIdx.y);
  else if (z == 1)
    gemm_body<1>(A1, B1, C1, M, N, K, blockIdx.x, blockIdx.y);
  else
    gemm_body<2>(A2, B2, C2, M, N, K, blockIdx.x, blockIdx.y);
}

// ================= WKV chunked scan, yT out [c][bt] =================
#define SEG 32
#define SL  32
__global__ __launch_bounds__(256) void wkv_chunked(
    const bf16* __restrict__ kT, const bf16* __restrict__ vT,
    const float* __restrict__ sd, const float* __restrict__ sf,
    bf16* __restrict__ yT) {
  int tid = threadIdx.x;
  int s = tid >> 3, cr = tid & 7;
  int b = blockIdx.x / 96, cg = blockIdx.x % 96;
  int c = cg * 8 + cr;
  float w = sd[c] * (1.0f / (float)T_);
  float u = sf[c] * (1.0f / (float)T_);
  size_t base = (size_t)c * M_ + b * T_ + s * SL;
  BV8 kv[4], vv8[4];
#pragma unroll
  for (int j = 0; j < 4; j++) {
    kv[j]  = *(const BV8*)(kT + base + j * 8);
    vv8[j] = *(const BV8*)(vT + base + j * 8);
  }
  float P = 0.f, Q = 0.f, O = -1e38f;
#pragma unroll
  for (int j = 0; j < 4; j++)
#pragma unroll
    for (int i = 0; i < 8; i++) {
      float kt = __bfloat162float(kv[j].v[i]);
      float vt = __bfloat162float(vv8[j].v[i]);
      float wo = w + O;
      float no = fmaxf(wo, kt);
      float A  = __expf(wo - no);
      float Bx = __expf(kt - no);
      P = A * P + Bx * vt;
      Q = A * Q + Bx;
      O = no;
    }
  __shared__ float sP[SEG][8], sQ[SEG][8], sO[SEG][8];
  sP[s][cr] = P; sQ[s][cr] = Q; sO[s][cr] = O;
  __syncthreads();
  if (s == 0) {
    float p = 0.f, q = 0.f, o = -1e38f;
    float dw = (float)SL * w;
#pragma unroll 1
    for (int t = 0; t < SEG; t++) {
      float Pp = sP[t][cr], Qq = sQ[t][cr], Oo = sO[t][cr];
      sP[t][cr] = p; sQ[t][cr] = q; sO[t][cr] = o;
      float a  = dw + o;
      float no = fmaxf(a, Oo);
      float e1 = __expf(a - no);
      float e2 = __expf(Oo - no);
      p = e1 * p + e2 * Pp;
      q = e1 * q + e2 * Qq;
      o = no;
    }
  }
  __syncthreads();
  float p = sP[s][cr], q = sQ[s][cr], o = sO[s][cr];
  BV8 yo[4];
#pragma unroll
  for (int j = 0; j < 4; j++)
#pragma unroll
    for (int i = 0; i < 8; i++) {
      float kt = __bfloat162float(kv[j].v[i]);
      float vt = __bfloat162float(vv8[j].v[i]);
      float uk = u + kt;
      float no = fmaxf(o, uk);
      float A  = __expf(o - no);
      float Bx = __expf(uk - no);
      yo[j].v[i] = __float2bfloat16(__fdividef(A * p + Bx * vt, A * q + Bx));
      float wo  = w + o;
      float no2 = fmaxf(wo, kt);
      float A2 = __expf(wo - no2);
      float B2 = __expf(kt - no2);
      p = A2 * p + B2 * vt;
      q = A2 * q + B2;
      o = no2;
    }
  bf16* yp = yT + base;
#pragma unroll
  for (int j = 0; j < 4; j++) *(BV8*)(yp + j * 8) = yo[j];
}

// ================= LN(yT)*srT -> z [bt][c] =================
// block: 256 thr = 4 c-splits x 64 bt ; grid: 256 blocks (64 bt each)
__global__ __launch_bounds__(256) void ln_srT_kernel(
    const bf16* __restrict__ yT, const bf16* __restrict__ srT,
    const float* __restrict__ gg, const float* __restrict__ bb,
    bf16* __restrict__ z) {
  int tid = threadIdx.x;
  int btl = tid & 63;
  int cs  = tid >> 6;          // 0..3, wave-uniform
  int bt0 = blockIdx.x * 64;
  int bt  = bt0 + btl;
  float s = 0.f, s2 = 0.f;
#pragma unroll 4
  for (int i = 0; i < 192; i++) {
    int c = cs * 192 + i;
    float v = __bfloat162float(yT[(size_t)c * M_ + bt]);
    s += v; s2 += v * v;
  }
  __shared__ float rs_[4][64], r2_[4][64];
  rs_[cs][btl] = s; r2_[cs][btl] = s2;
  __syncthreads();
  __shared__ float mu_[64], sig_[64];
  if (tid < 64) {
    float ts = rs_[0][tid] + rs_[1][tid] + rs_[2][tid] + rs_[3][tid];
    float t2 = r2_[0][tid] + r2_[1][tid] + r2_[2][tid] + r2_[3][tid];
    float mu  = ts * (1.0f / (float)C_);
    float var = t2 * (1.0f / (float)C_) - mu * mu;
    mu_[tid]  = mu;
    sig_[tid] = rsqrtf(var + 1e-5f);
  }
  __syncthreads();
  float mu = mu_[btl], rs = sig_[btl];
  __shared__ bf16 tile[64 * 72];   // row stride 72 (144B, 16B-aligned)
  for (int ch = 0; ch < 12; ch++) {
    int cbase = ch * 64;
#pragma unroll
    for (int i = 0; i < 16; i++) {
      int c = cbase + cs * 16 + i;
      float v  = __bfloat162float(yT[(size_t)c * M_ + bt]);
      float sr = __bfloat162float(srT[(size_t)c * M_ + bt]);
      float zv = ((v - mu) * rs * gg[c] + bb[c]) * sr;
      tile[btl * 72 + cs * 16 + i] = __float2bfloat16(zv);
    }
    __syncthreads();
#pragma unroll
    for (int sw = 0; sw < 2; sw++) {
      int r  = (tid >> 3) + sw * 32;
      int cc = (tid & 7) * 8;
      BV8 val = *(const BV8*)&tile[r * 72 + cc];
      *(BV8*)(z + (size_t)(bt0 + r) * C_ + cbase + cc) = val;
    }
    __syncthreads();
  }
}

extern "C" void kernel_launch(void* const* d_in, const int* in_sizes, int n_in,
                              void* d_out, int out_size, void* d_ws, size_t ws_size,
                              hipStream_t stream) {
  const float* x  = (const float*)d_in[0];
  const float* sd = (const float*)d_in[3];
  const float* sf = (const float*)d_in[4];
  const float* mk = (const float*)d_in[5];
  const float* mv = (const float*)d_in[6];
  const float* mr = (const float*)d_in[7];
  const float* Wk = (const float*)d_in[8];
  const float* Wv = (const float*)d_in[9];
  const float* Wr = (const float*)d_in[10];
  const float* Wo = (const float*)d_in[11];
  const float* lg = (const float*)d_in[12];
  const float* lb = (const float*)d_in[13];

  char* ws = (char*)d_ws;
  bf16* xk  = (bf16*)(ws + OFF_XK);
  bf16* xv  = (bf16*)(ws + OFF_XV);
  bf16* xr  = (bf16*)(ws + OFF_XR);
  bf16* kTb = (bf16*)(ws + OFF_K);
  bf16* vTb = (bf16*)(ws + OFF_V);
  bf16* srT = (bf16*)(ws + OFF_SR);
  bf16* wt  = (bf16*)(ws + OFF_WT);
  bf16* WkT = wt;
  bf16* WvT = wt + (size_t)C_ * C_;
  bf16* WrT = wt + (size_t)2 * C_ * C_;
  bf16* WoT = wt + (size_t)3 * C_ * C_;
  bf16* yTb = (bf16*)(ws + OFF_Y);
  bf16* zb  = (bf16*)(ws + OFF_Z);

  prep_kernel<<<8448, 256, 0, stream>>>(x, mk, mv, mr, Wk, Wv, Wr, Wo,
                                        xk, xv, xr, wt);

  gemm_mix3<<<dim3(M_ / 128, C_ / 128, 3), 256, 0, stream>>>(
      WkT, xk, kTb, WvT, xv, vTb, WrT, xr, srT, C_, M_, C_);

  wkv_chunked<<<B_ * 96, 256, 0, stream>>>(kTb, vTb, sd, sf, yTb);
  ln_srT_kernel<<<M_ / 64, 256, 0, stream>>>(yTb, srT, lg, lb, zb);

  gemm_bt<3><<<dim3(C_ / 128, M_ / 128), 256, 0, stream>>>(
      zb, WoT, (float*)d_out, M_, C_, C_);
}

// Round 6
// 290.456 us; speedup vs baseline: 1.1887x; 1.1887x over previous
//
#include <hip/hip_runtime.h>
#include <hip/hip_bf16.h>

using bf16 = __hip_bfloat16;
typedef __attribute__((ext_vector_type(8))) __bf16 bf16x8;
typedef __attribute__((ext_vector_type(4))) float floatx4;

#define B_  16
#define T_  1024
#define C_  768
#define M_  16384  // B_*T_

#define OFF_XK ((size_t)0)
#define OFF_XV ((size_t)25165824)
#define OFF_XR ((size_t)50331648)
#define OFF_K  ((size_t)75497472)
#define OFF_V  ((size_t)100663296)
#define OFF_SR ((size_t)125829120)
#define OFF_WT ((size_t)150994944)
#define OFF_Y  ((size_t)0)          // bf16 y[bt][c] aliases xk (dead after mix3)
#define OFF_Z  ((size_t)50331648)   // bf16 z aliases xr (dead after mix3)

struct __align__(16) BV8 { bf16 v[8]; };

// ================= prep: transpose_w + shift_mix merged =================
__global__ __launch_bounds__(256) void prep_kernel(
    const float* __restrict__ x,
    const float* __restrict__ mk, const float* __restrict__ mv, const float* __restrict__ mr,
    const float* __restrict__ w0, const float* __restrict__ w1,
    const float* __restrict__ w2, const float* __restrict__ w3,
    bf16* __restrict__ xk, bf16* __restrict__ xv, bf16* __restrict__ xr,
    bf16* __restrict__ wt) {
  __shared__ float tile[32 * 33];
  int bid = blockIdx.x;
  if (bid < 6144) {
    int gid = bid * 256 + threadIdx.x;
    int c8 = gid % 96;
    int bt = gid / 96;
    int b  = bt >> 10;
    int t  = bt & 1023;
    int hh = t >> 5, ww = t & 31;
    int c0 = c8 * 8;
    int g  = c8 / 24;
    int sh = hh, sw = ww;
    bool valid;
    if (g == 0)      { sw = ww - 1; valid = (ww >= 1);  }
    else if (g == 1) { sw = ww + 1; valid = (ww <= 30); }
    else if (g == 2) { sh = hh - 1; valid = (hh >= 1);  }
    else             { sh = hh + 1; valid = (hh <= 30); }
    size_t off = (size_t)bt * C_ + c0;
    float xs[8], ss[8];
    *(float4*)(xs)     = *(const float4*)(x + off);
    *(float4*)(xs + 4) = *(const float4*)(x + off + 4);
    if (valid) {
      size_t soff = (size_t)(b * 1024 + sh * 32 + sw) * C_ + c0;
      *(float4*)(ss)     = *(const float4*)(x + soff);
      *(float4*)(ss + 4) = *(const float4*)(x + soff + 4);
    } else {
#pragma unroll
      for (int j = 0; j < 8; j++) ss[j] = 0.f;
    }
    BV8 ok, ov, orr;
#pragma unroll
    for (int j = 0; j < 8; j++) {
      float xf = xs[j], sf = ss[j];
      float a  = mk[c0 + j];
      float bm = mv[c0 + j];
      float cm = mr[c0 + j];
      ok.v[j]  = __float2bfloat16(xf * a  + sf * (1.f - a));
      ov.v[j]  = __float2bfloat16(xf * bm + sf * (1.f - bm));
      orr.v[j] = __float2bfloat16(xf * cm + sf * (1.f - cm));
    }
    *(BV8*)(xk + off) = ok;
    *(BV8*)(xv + off) = ov;
    *(BV8*)(xr + off) = orr;
  } else {
    int tb = bid - 6144;
    int which = tb / 576;
    int rem   = tb % 576;
    int by = rem / 24, bx = rem % 24;
    const float* src = which == 0 ? w0 : which == 1 ? w1 : which == 2 ? w2 : w3;
    bf16* dst = wt + (size_t)which * (C_ * C_);
    int k0 = by * 32;
    int n0 = bx * 32;
    int j  = threadIdx.x & 31;
    int i0 = threadIdx.x >> 5;
#pragma unroll
    for (int s = 0; s < 4; s++) {
      int i = i0 + s * 8;
      tile[i * 33 + j] = src[(size_t)(k0 + i) * C_ + n0 + j];
    }
    __syncthreads();
#pragma unroll
    for (int s = 0; s < 4; s++) {
      int i = i0 + s * 8;
      dst[(size_t)(n0 + i) * C_ + k0 + j] = __float2bfloat16(tile[j * 33 + i]);
    }
  }
}

// ---- shared GEMM body: 128x128 tile, BK=64 as two BK=32 panels ----
// Runtime mode: 1 = bf16 store, 2 = sigmoid->bf16, 3 = fp32 store.
// Single instantiation => single 32 KB static LDS allocation.
__device__ __forceinline__ void gemm_body(
    const bf16* __restrict__ A, const bf16* __restrict__ BT,
    void* __restrict__ Cout, int M, int N, int K,
    int bx, int by, int mode) {
  __shared__ bf16 As[128 * 64];
  __shared__ bf16 Bs[128 * 64];
  int tid  = threadIdx.x;
  int wave = tid >> 6, lane = tid & 63;
  int wm = (wave & 1) * 64, wn = (wave >> 1) * 64;
  size_t m0 = (size_t)by * 128, n0 = (size_t)bx * 128;

  floatx4 acc[4][4];
#pragma unroll
  for (int i = 0; i < 4; i++)
#pragma unroll
    for (int j = 0; j < 4; j++) acc[i][j] = (floatx4){0.f, 0.f, 0.f, 0.f};

  int srow[4], skk[4];
#pragma unroll
  for (int i = 0; i < 4; i++) {
    srow[i] = ((tid >> 2) + i * 64) & 127;
    skk[i]  = (tid & 3) * 8 + (i >> 1) * 32;
  }
  bf16* lA = As + tid * 8;
  bf16* lB = Bs + tid * 8;
  int fr  = lane & 15;
  int fko = (lane >> 4) * 8;

  for (int k0 = 0; k0 < K; k0 += 64) {
#pragma unroll
    for (int i = 0; i < 4; i++) {
      __builtin_amdgcn_global_load_lds(
          (const __attribute__((address_space(1))) void*)(A + (m0 + srow[i]) * (size_t)K + k0 + skk[i]),
          (__attribute__((address_space(3))) void*)(lA + i * 2048), 16, 0, 0);
      __builtin_amdgcn_global_load_lds(
          (const __attribute__((address_space(1))) void*)(BT + (n0 + srow[i]) * (size_t)K + k0 + skk[i]),
          (__attribute__((address_space(3))) void*)(lB + i * 2048), 16, 0, 0);
    }
    __syncthreads();
#pragma unroll
    for (int s = 0; s < 2; s++) {
      bf16x8 af[4], bfr[4];
#pragma unroll
      for (int mi = 0; mi < 4; mi++)
        af[mi] = *(const bf16x8*)(As + s * 4096 + (wm + mi * 16 + fr) * 32 + fko);
#pragma unroll
      for (int ni = 0; ni < 4; ni++)
        bfr[ni] = *(const bf16x8*)(Bs + s * 4096 + (wn + ni * 16 + fr) * 32 + fko);
#pragma unroll
      for (int mi = 0; mi < 4; mi++)
#pragma unroll
        for (int ni = 0; ni < 4; ni++)
          acc[mi][ni] = __builtin_amdgcn_mfma_f32_16x16x32_bf16(
              af[mi], bfr[ni], acc[mi][ni], 0, 0, 0);
    }
    __syncthreads();
  }
  int cr = (lane >> 4) * 4;
  int cc = lane & 15;
#pragma unroll
  for (int mi = 0; mi < 4; mi++)
#pragma unroll
    for (int ni = 0; ni < 4; ni++)
#pragma unroll
      for (int i = 0; i < 4; i++) {
        size_t r   = m0 + wm + mi * 16 + cr + i;
        size_t col = n0 + wn + ni * 16 + cc;
        float val = acc[mi][ni][i];
        if (mode == 3) {
          ((float*)Cout)[r * N + col] = val;
        } else {
          if (mode == 2) val = 1.0f / (1.0f + __expf(-val));
          ((bf16*)Cout)[r * N + col] = __float2bfloat16(val);
        }
      }
}

// merged k^T / v^T / sr GEMM: z selects operands; z==2 swaps grid axes
// grid: (128, 6, 3)
__global__ __launch_bounds__(256, 2) void gemm_mix3(
    const bf16* __restrict__ WkT, const bf16* __restrict__ xk, bf16* __restrict__ kT,
    const bf16* __restrict__ WvT, const bf16* __restrict__ xv, bf16* __restrict__ vT,
    const bf16* __restrict__ xr,  const bf16* __restrict__ WrT, bf16* __restrict__ sr) {
  int z = blockIdx.z;
  if (z == 0)
    gemm_body(WkT, xk, kT, C_, M_, C_, blockIdx.x, blockIdx.y, 1);
  else if (z == 1)
    gemm_body(WvT, xv, vT, C_, M_, C_, blockIdx.x, blockIdx.y, 1);
  else
    gemm_body(xr, WrT, sr, M_, C_, C_, blockIdx.y, blockIdx.x, 2);
}

__global__ __launch_bounds__(256, 2) void gemm_out(
    const bf16* __restrict__ A, const bf16* __restrict__ BT,
    float* __restrict__ Cout) {
  gemm_body(A, BT, Cout, M_, C_, C_, blockIdx.x, blockIdx.y, 3);
}

// ================= WKV chunked scan, y out [bt][c] bf16 =================
#define SEG 32
#define SL  32
__global__ __launch_bounds__(256) void wkv_chunked(
    const bf16* __restrict__ kT, const bf16* __restrict__ vT,
    const float* __restrict__ sd, const float* __restrict__ sf,
    bf16* __restrict__ y) {
  int tid = threadIdx.x;
  int s = tid >> 3, cr = tid & 7;
  int b = blockIdx.x / 96, cg = blockIdx.x % 96;
  int c = cg * 8 + cr;
  float w = sd[c] * (1.0f / (float)T_);
  float u = sf[c] * (1.0f / (float)T_);
  size_t base = (size_t)c * M_ + b * T_ + s * SL;
  BV8 kv[4], vv8[4];
#pragma unroll
  for (int j = 0; j < 4; j++) {
    kv[j]  = *(const BV8*)(kT + base + j * 8);
    vv8[j] = *(const BV8*)(vT + base + j * 8);
  }
  float P = 0.f, Q = 0.f, O = -1e38f;
#pragma unroll
  for (int j = 0; j < 4; j++)
#pragma unroll
    for (int i = 0; i < 8; i++) {
      float kt = __bfloat162float(kv[j].v[i]);
      float vt = __bfloat162float(vv8[j].v[i]);
      float wo = w + O;
      float no = fmaxf(wo, kt);
      float A  = __expf(wo - no);
      float Bx = __expf(kt - no);
      P = A * P + Bx * vt;
      Q = A * Q + Bx;
      O = no;
    }
  __shared__ float sP[SEG][8], sQ[SEG][8], sO[SEG][8];
  sP[s][cr] = P; sQ[s][cr] = Q; sO[s][cr] = O;
  __syncthreads();
  if (s == 0) {
    float p = 0.f, q = 0.f, o = -1e38f;
    float dw = (float)SL * w;
#pragma unroll 1
    for (int t = 0; t < SEG; t++) {
      float Pp = sP[t][cr], Qq = sQ[t][cr], Oo = sO[t][cr];
      sP[t][cr] = p; sQ[t][cr] = q; sO[t][cr] = o;
      float a  = dw + o;
      float no = fmaxf(a, Oo);
      float e1 = __expf(a - no);
      float e2 = __expf(Oo - no);
      p = e1 * p + e2 * Pp;
      q = e1 * q + e2 * Qq;
      o = no;
    }
  }
  __syncthreads();
  float p = sP[s][cr], q = sQ[s][cr], o = sO[s][cr];
  bf16* yp = y + ((size_t)(b * T_ + s * SL)) * C_ + c;
#pragma unroll
  for (int j = 0; j < 4; j++)
#pragma unroll
    for (int i = 0; i < 8; i++) {
      float kt = __bfloat162float(kv[j].v[i]);
      float vt = __bfloat162float(vv8[j].v[i]);
      float uk = u + kt;
      float no = fmaxf(o, uk);
      float A  = __expf(o - no);
      float Bx = __expf(uk - no);
      yp[(size_t)(j * 8 + i) * C_] =
          __float2bfloat16(__fdividef(A * p + Bx * vt, A * q + Bx));
      float wo  = w + o;
      float no2 = fmaxf(wo, kt);
      float A2 = __expf(wo - no2);
      float B2 = __expf(kt - no2);
      p = A2 * p + B2 * vt;
      q = A2 * q + B2;
      o = no2;
    }
}

// ================= LayerNorm(y)*sr -> z (bf16), row-major =================
__global__ __launch_bounds__(256) void ln_sr_kernel(
    const bf16* __restrict__ y, const bf16* __restrict__ sr,
    const float* __restrict__ gg, const float* __restrict__ bb,
    bf16* __restrict__ z) {
  int rowi = blockIdx.x;
  size_t base = (size_t)rowi * C_;
  int tid = threadIdx.x;
  float v0 = __bfloat162float(y[base + tid]);
  float v1 = __bfloat162float(y[base + tid + 256]);
  float v2 = __bfloat162float(y[base + tid + 512]);
  float s  = v0 + v1 + v2;
  float s2 = v0 * v0 + v1 * v1 + v2 * v2;
#pragma unroll
  for (int off = 32; off > 0; off >>= 1) {
    s  += __shfl_down(s, off);
    s2 += __shfl_down(s2, off);
  }
  __shared__ float red[16];
  int wv = tid >> 6, ln = tid & 63;
  if (ln == 0) { red[wv] = s; red[8 + wv] = s2; }
  __syncthreads();
  if (tid == 0) {
    float ts = red[0] + red[1] + red[2] + red[3];
    float t2 = red[8] + red[9] + red[10] + red[11];
    float mu  = ts * (1.0f / (float)C_);
    float var = t2 * (1.0f / (float)C_) - mu * mu;
    red[0] = mu;
    red[1] = rsqrtf(var + 1e-5f);
  }
  __syncthreads();
  float mu = red[0], rs = red[1];
#pragma unroll
  for (int j = 0; j < 3; j++) {
    int c = tid + j * 256;
    float val = (j == 0 ? v0 : (j == 1 ? v1 : v2));
    float gn  = gg[c];
    float bn  = bb[c];
    float srf = __bfloat162float(sr[base + c]);
    z[base + c] = __float2bfloat16(((val - mu) * rs * gn + bn) * srf);
  }
}

extern "C" void kernel_launch(void* const* d_in, const int* in_sizes, int n_in,
                              void* d_out, int out_size, void* d_ws, size_t ws_size,
                              hipStream_t stream) {
  const float* x  = (const float*)d_in[0];
  const float* sd = (const float*)d_in[3];
  const float* sf = (const float*)d_in[4];
  const float* mk = (const float*)d_in[5];
  const float* mv = (const float*)d_in[6];
  const float* mr = (const float*)d_in[7];
  const float* Wk = (const float*)d_in[8];
  const float* Wv = (const float*)d_in[9];
  const float* Wr = (const float*)d_in[10];
  const float* Wo = (const float*)d_in[11];
  const float* lg = (const float*)d_in[12];
  const float* lb = (const float*)d_in[13];

  char* ws = (char*)d_ws;
  bf16* xk  = (bf16*)(ws + OFF_XK);
  bf16* xv  = (bf16*)(ws + OFF_XV);
  bf16* xr  = (bf16*)(ws + OFF_XR);
  bf16* kTb = (bf16*)(ws + OFF_K);
  bf16* vTb = (bf16*)(ws + OFF_V);
  bf16* srb = (bf16*)(ws + OFF_SR);
  bf16* wt  = (bf16*)(ws + OFF_WT);
  bf16* WkT = wt;
  bf16* WvT = wt + (size_t)C_ * C_;
  bf16* WrT = wt + (size_t)2 * C_ * C_;
  bf16* WoT = wt + (size_t)3 * C_ * C_;
  bf16* yb  = (bf16*)(ws + OFF_Y);
  bf16* zb  = (bf16*)(ws + OFF_Z);

  prep_kernel<<<8448, 256, 0, stream>>>(x, mk, mv, mr, Wk, Wv, Wr, Wo,
                                        xk, xv, xr, wt);

  gemm_mix3<<<dim3(M_ / 128, C_ / 128, 3), 256, 0, stream>>>(
      WkT, xk, kTb, WvT, xv, vTb, xr, WrT, srb);

  wkv_chunked<<<B_ * 96, 256, 0, stream>>>(kTb, vTb, sd, sf, yb);
  ln_sr_kernel<<<M_, 256, 0, stream>>>(yb, srb, lg, lb, zb);

  gemm_out<<<dim3(C_ / 128, M_ / 128), 256, 0, stream>>>(zb, WoT, (float*)d_out);
}